// Round 2
// baseline (196.837 us; speedup 1.0000x reference)
//
#include <hip/hip_runtime.h>
#include <hip/hip_bf16.h>

// Shapes (fixed problem)
#define BSZ   8192
#define DIN   1024
#define DOUT  512
#define NEXP  4

typedef __attribute__((ext_vector_type(8))) short short8;
typedef __attribute__((ext_vector_type(4))) float f32x4;

// ---------- helpers ----------
static __device__ inline unsigned short f32_to_bf16_rne(float f) {
    unsigned int u = __float_as_uint(f);
    unsigned int r = 0x7FFFu + ((u >> 16) & 1u);
    u += r;
    return (unsigned short)(u >> 16);
}

static __device__ inline float block_reduce_sum(float v, float* sred) {
    // 256 threads = 4 waves of 64
    for (int off = 32; off > 0; off >>= 1) v += __shfl_down(v, off, 64);
    int lane = threadIdx.x & 63, w = threadIdx.x >> 6;
    if (lane == 0) sred[w] = v;
    __syncthreads();
    float r = sred[0] + sred[1] + sred[2] + sred[3];
    __syncthreads();
    return r;
}

#define GLD_LDS16(g, l)                                                        \
    __builtin_amdgcn_global_load_lds(                                          \
        (const __attribute__((address_space(1))) void*)(g),                    \
        (__attribute__((address_space(3))) void*)(l), 16, 0, 0)

// ---------- 1. convert x -> bf16 ----------
__global__ void convx_kernel(const float* __restrict__ x,
                             unsigned short* __restrict__ xb) {
    size_t i = ((size_t)blockIdx.x * 256 + threadIdx.x) * 8;
    float4 v0 = *(const float4*)&x[i];
    float4 v1 = *(const float4*)&x[i + 4];
    unsigned short tmp[8] = {
        f32_to_bf16_rne(v0.x), f32_to_bf16_rne(v0.y),
        f32_to_bf16_rne(v0.z), f32_to_bf16_rne(v0.w),
        f32_to_bf16_rne(v1.x), f32_to_bf16_rne(v1.y),
        f32_to_bf16_rne(v1.z), f32_to_bf16_rne(v1.w)};
    *(short8*)&xb[i] = *(short8*)tmp;
}

// ---------- 2. convert W[e][k][n] -> Wt[e][n][k] bf16 (LDS-tiled transpose) --
__global__ void convwt_kernel(const float* __restrict__ W,
                              unsigned short* __restrict__ Wt) {
    __shared__ float tile[32][33];
    int n0 = blockIdx.x * 32, k0 = blockIdx.y * 32, e = blockIdx.z;
    int c = threadIdx.x & 31, r4 = threadIdx.x >> 5;  // r4: 0..7
    const float* Wp = W + ((size_t)e * DIN + k0) * DOUT + n0;
#pragma unroll
    for (int i = 0; i < 4; ++i) {
        int r = r4 + i * 8;
        tile[r][c] = Wp[(size_t)r * DOUT + c];
    }
    __syncthreads();
    unsigned short* Wtp = Wt + ((size_t)e * DOUT + n0) * DIN + k0;
#pragma unroll
    for (int i = 0; i < 4; ++i) {
        int r = r4 + i * 8;
        Wtp[(size_t)r * DIN + c] = f32_to_bf16_rne(tile[c][r]);
    }
}

// ---------- 3. GEMM: logits[e][b][n] = x[b][:] . W[e][:][n] + bias[e][n] ----
// 128x128 tile, BK=32, 4 waves, 4x4 16x16x32 bf16 MFMA frags per wave.
__global__ __launch_bounds__(256) void gemm_kernel(
    const unsigned short* __restrict__ xb,
    const unsigned short* __restrict__ wtb,
    const float* __restrict__ bias,
    float* __restrict__ logits) {
    __shared__ unsigned short As[128 * 32];
    __shared__ unsigned short Bs[128 * 32];
    const int tid = threadIdx.x;
    const int e = blockIdx.z;
    const int m0 = blockIdx.y * 128;
    const int n0 = blockIdx.x * 128;
    const unsigned short* Ag = xb + (size_t)m0 * DIN;
    const unsigned short* Bg = wtb + ((size_t)e * DOUT + n0) * DIN;

    const int lane = tid & 63, w = tid >> 6;
    const int wm = (w >> 1) * 64, wn = (w & 1) * 64;
    const int kk = (lane >> 4) * 8, rr = lane & 15;

    f32x4 acc[4][4] = {};

    const int f = tid;             // staging lane id for issue 0
    const int row0 = f >> 2, seg0 = f & 3;
    const int f1 = 256 + tid;
    const int row1 = f1 >> 2, seg1 = f1 & 3;

    for (int kt = 0; kt < DIN / 32; ++kt) {
        const int k0 = kt * 32;
        // stage A and B tiles: 8KB each, 2 issues of 4KB per tile
        GLD_LDS16(Ag + (size_t)row0 * DIN + k0 + seg0 * 8, As + f * 8);
        GLD_LDS16(Bg + (size_t)row0 * DIN + k0 + seg0 * 8, Bs + f * 8);
        GLD_LDS16(Ag + (size_t)row1 * DIN + k0 + seg1 * 8, As + f1 * 8);
        GLD_LDS16(Bg + (size_t)row1 * DIN + k0 + seg1 * 8, Bs + f1 * 8);
        __syncthreads();

        short8 a[4], b[4];
#pragma unroll
        for (int i = 0; i < 4; ++i)
            a[i] = *(const short8*)&As[(wm + i * 16 + rr) * 32 + kk];
#pragma unroll
        for (int i = 0; i < 4; ++i)
            b[i] = *(const short8*)&Bs[(wn + i * 16 + rr) * 32 + kk];
#pragma unroll
        for (int i = 0; i < 4; ++i)
#pragma unroll
            for (int j = 0; j < 4; ++j)
                acc[i][j] = __builtin_amdgcn_mfma_f32_16x16x32_bf16(
                    a[i], b[j], acc[i][j], 0, 0, 0);
        __syncthreads();
    }

    // epilogue: D[row=(lane>>4)*4+r][col=lane&15] per 16x16 frag; fused bias
#pragma unroll
    for (int j = 0; j < 4; ++j) {
        const int gc = n0 + wn + j * 16 + rr;
        const float bv = bias[e * DOUT + gc];
#pragma unroll
        for (int i = 0; i < 4; ++i) {
            const int gr = m0 + wm + i * 16 + (lane >> 4) * 4;
            float* cp = logits + ((size_t)e * BSZ + gr) * DOUT + gc;
#pragma unroll
            for (int r = 0; r < 4; ++r)
                cp[(size_t)r * DOUT] = acc[i][j][r] + bv;
        }
    }
}

// ---------- 4. per-batch row stats: normalize in place, compute ev ----------
__global__ void rowstats_kernel(float* __restrict__ xi,
                                float* __restrict__ ev) {
    const int b = blockIdx.x, t = threadIdx.x;
    __shared__ float sred[4];
    float Tv[3], Pv[2];
    float pe0 = 0.f, pe1 = 0.f;
    for (int e = 0; e < NEXP; ++e) {
        float* row = xi + ((size_t)e * BSZ + b) * DOUT;
        float2 v = *(float2*)&row[t * 2];
        float ss = block_reduce_sum(v.x * v.x + v.y * v.y, sred);
        float nrm = sqrtf(ss);
        float rinv = 1.0f / fmaxf(nrm, 1e-12f);
        v.x *= rinv; v.y *= rinv;
        *(float2*)&row[t * 2] = v;
        float e0 = expf(v.x), e1 = expf(v.y);
        if (e < 3) {
            Tv[e] = block_reduce_sum(e0 + e1, sred);
            if (e > 0)
                Pv[e - 1] = block_reduce_sum(pe0 * e0 + pe1 * e1, sred);
        }
        pe0 = e0; pe1 = e1;
    }
    if (t == 0) {
        const float d = (float)DOUT;
        float S0 = Tv[0] + d, S1 = Tv[1] + d, S2 = Tv[2] + d;
        float u0 = d / S0, u1 = d / S1, u2 = d / S2;
        float sb0 = Tv[0] / S0, sb1 = Tv[1] / S1, sb2 = Tv[2] / S2;
        float C1 = sb0 * sb1 - Pv[0] / (S0 * S1);
        float C2 = sb1 * sb2 - Pv[1] / (S1 * S2);
        float w0 = 1.0f;
        float w1 = u0;
        float w2 = w1 * u1 / (1.0f - C1);
        float w3 = w2 * u2 / (1.0f - C2);
        ev[0 * BSZ + b] = expf(w0 / 0.2f);
        ev[1 * BSZ + b] = expf(w1 / 0.2f);
        ev[2 * BSZ + b] = expf(w2 / 0.2f);
        ev[3 * BSZ + b] = expf(w3 / 0.2f);
    }
}

// ---------- 5. Z reduce per expert ----------
__global__ void zred_kernel(const float* __restrict__ ev,
                            float* __restrict__ invZ) {
    const int i = blockIdx.x, t = threadIdx.x;
    __shared__ float sred[4];
    float s = 0.f;
    for (int b = t; b < BSZ; b += 256) s += ev[(size_t)i * BSZ + b];
    s = block_reduce_sum(s, sred);
    if (t == 0) invZ[i] = 1.0f / s;
}

// ---------- 6. weighted output ----------
__global__ void outk_kernel(const float* __restrict__ xi,
                            const float* __restrict__ ev,
                            const float* __restrict__ invZ,
                            float* __restrict__ out) {
    const int b = blockIdx.x, t = threadIdx.x;
    float wgt[NEXP];
#pragma unroll
    for (int e = 0; e < NEXP; ++e) wgt[e] = ev[(size_t)e * BSZ + b] * invZ[e];
    float2 o = {0.f, 0.f};
#pragma unroll
    for (int e = 0; e < NEXP; ++e) {
        float2 v = *(const float2*)&xi[((size_t)e * BSZ + b) * DOUT + t * 2];
        o.x += v.x * wgt[e];
        o.y += v.y * wgt[e];
    }
    *(float2*)&out[(size_t)b * DOUT + t * 2] = o;
}

// ---------- launch ----------
extern "C" void kernel_launch(void* const* d_in, const int* in_sizes, int n_in,
                              void* d_out, int out_size, void* d_ws,
                              size_t ws_size, hipStream_t stream) {
    const float* x = (const float*)d_in[0];
    const float* W = (const float*)d_in[1];
    const float* bias = (const float*)d_in[2];
    float* out = (float*)d_out;

    char* ws = (char*)d_ws;
    // layout: logits/xi [4][8192][512] f32 = 64MB | xb 16MB | wtb 4MB | ev 128KB | invZ
    float* logits = (float*)ws;
    unsigned short* xb = (unsigned short*)(ws + (size_t)67108864);
    unsigned short* wtb = (unsigned short*)(ws + (size_t)83886080);
    float* ev = (float*)(ws + (size_t)88080384);
    float* invZ = (float*)(ws + (size_t)88211456);

    // 1. x -> bf16   (8192*1024 / (256*8) = 4096 blocks)
    convx_kernel<<<4096, 256, 0, stream>>>(x, xb);
    // 2. W -> bf16 transposed
    convwt_kernel<<<dim3(DOUT / 32, DIN / 32, NEXP), 256, 0, stream>>>(W, wtb);
    // 3. GEMM + bias
    gemm_kernel<<<dim3(DOUT / 128, BSZ / 128, NEXP), 256, 0, stream>>>(
        xb, wtb, bias, logits);
    // 4. row stats (normalize in place, ev weights)
    rowstats_kernel<<<BSZ, 256, 0, stream>>>(logits, ev);
    // 5. Z per expert
    zred_kernel<<<NEXP, 256, 0, stream>>>(ev, invZ);
    // 6. weighted sum
    outk_kernel<<<BSZ, 256, 0, stream>>>(logits, ev, invZ, out);
}

// Round 3
// 161.354 us; speedup vs baseline: 1.2199x; 1.2199x over previous
//
#include <hip/hip_runtime.h>
#include <hip/hip_bf16.h>

// Shapes (fixed problem)
#define BSZ   8192
#define DIN   1024
#define DOUT  512
#define NEXP  4

typedef __attribute__((ext_vector_type(8))) short short8;
typedef __attribute__((ext_vector_type(4))) float f32x4;

// ---------- helpers ----------
static __device__ inline unsigned short f32_to_bf16_rne(float f) {
    unsigned int u = __float_as_uint(f);
    unsigned int r = 0x7FFFu + ((u >> 16) & 1u);
    u += r;
    return (unsigned short)(u >> 16);
}

static __device__ inline float bf16_to_f32(unsigned short u) {
    return __uint_as_float(((unsigned int)u) << 16);
}

static __device__ inline float wred(float v) {  // full-wave butterfly sum
    for (int off = 1; off < 64; off <<= 1) v += __shfl_xor(v, off, 64);
    return v;
}

#define GLD_LDS16(g, l)                                                        \
    __builtin_amdgcn_global_load_lds(                                          \
        (const __attribute__((address_space(1))) void*)(g),                    \
        (__attribute__((address_space(3))) void*)(l), 16, 0, 0)

// ---------- 1. convert x -> bf16 ----------
__global__ void convx_kernel(const float* __restrict__ x,
                             unsigned short* __restrict__ xb) {
    size_t i = ((size_t)blockIdx.x * 256 + threadIdx.x) * 8;
    float4 v0 = *(const float4*)&x[i];
    float4 v1 = *(const float4*)&x[i + 4];
    unsigned short tmp[8] = {
        f32_to_bf16_rne(v0.x), f32_to_bf16_rne(v0.y),
        f32_to_bf16_rne(v0.z), f32_to_bf16_rne(v0.w),
        f32_to_bf16_rne(v1.x), f32_to_bf16_rne(v1.y),
        f32_to_bf16_rne(v1.z), f32_to_bf16_rne(v1.w)};
    *(short8*)&xb[i] = *(short8*)tmp;
}

// ---------- 2. convert W[e][k][n] -> Wt[e][n][k] bf16 (LDS-tiled transpose) --
__global__ void convwt_kernel(const float* __restrict__ W,
                              unsigned short* __restrict__ Wt) {
    __shared__ float tile[32][33];
    int n0 = blockIdx.x * 32, k0 = blockIdx.y * 32, e = blockIdx.z;
    int c = threadIdx.x & 31, r4 = threadIdx.x >> 5;  // r4: 0..7
    const float* Wp = W + ((size_t)e * DIN + k0) * DOUT + n0;
#pragma unroll
    for (int i = 0; i < 4; ++i) {
        int r = r4 + i * 8;
        tile[r][c] = Wp[(size_t)r * DOUT + c];
    }
    __syncthreads();
    unsigned short* Wtp = Wt + ((size_t)e * DOUT + n0) * DIN + k0;
#pragma unroll
    for (int i = 0; i < 4; ++i) {
        int r = r4 + i * 8;
        Wtp[(size_t)r * DIN + c] = f32_to_bf16_rne(tile[c][r]);
    }
}

// ---------- 3. GEMM: logits[e][b][n] = x[b][:].W[e][:][n] + bias -> bf16 ----
// 128x128 tile, BK=32, 4 waves, 4x4 16x16x32 bf16 MFMA frags per wave.
// 1D grid of 1024 with XCD-chunked swizzle: each XCD gets 8 contiguous
// m-panels x all 16 (e,n) combos, so A-panels are L2-resident per XCD.
__global__ __launch_bounds__(256) void gemm_kernel(
    const unsigned short* __restrict__ xb,
    const unsigned short* __restrict__ wtb,
    const float* __restrict__ bias,
    unsigned short* __restrict__ lgts) {
    __shared__ unsigned short As[128 * 32];
    __shared__ unsigned short Bs[128 * 32];
    const int tid = threadIdx.x;

    // bijective XCD swizzle (1024 % 8 == 0)
    const int bid = blockIdx.x;
    const int swz = (bid & 7) * 128 + (bid >> 3);
    const int mt = swz >> 4;          // 0..63
    const int e  = (swz >> 2) & 3;    // 0..3
    const int nt = swz & 3;           // 0..3
    const int m0 = mt * 128;
    const int n0 = nt * 128;

    const unsigned short* Ag = xb + (size_t)m0 * DIN;
    const unsigned short* Bg = wtb + ((size_t)e * DOUT + n0) * DIN;

    const int lane = tid & 63, w = tid >> 6;
    const int wm = (w >> 1) * 64, wn = (w & 1) * 64;
    const int kk = (lane >> 4) * 8, rr = lane & 15;

    f32x4 acc[4][4] = {};

    const int f = tid;
    const int row0 = f >> 2, seg0 = f & 3;
    const int f1 = 256 + tid;
    const int row1 = f1 >> 2, seg1 = f1 & 3;

    for (int kt = 0; kt < DIN / 32; ++kt) {
        const int k0 = kt * 32;
        GLD_LDS16(Ag + (size_t)row0 * DIN + k0 + seg0 * 8, As + f * 8);
        GLD_LDS16(Bg + (size_t)row0 * DIN + k0 + seg0 * 8, Bs + f * 8);
        GLD_LDS16(Ag + (size_t)row1 * DIN + k0 + seg1 * 8, As + f1 * 8);
        GLD_LDS16(Bg + (size_t)row1 * DIN + k0 + seg1 * 8, Bs + f1 * 8);
        __syncthreads();

        short8 a[4], b[4];
#pragma unroll
        for (int i = 0; i < 4; ++i)
            a[i] = *(const short8*)&As[(wm + i * 16 + rr) * 32 + kk];
#pragma unroll
        for (int i = 0; i < 4; ++i)
            b[i] = *(const short8*)&Bs[(wn + i * 16 + rr) * 32 + kk];
#pragma unroll
        for (int i = 0; i < 4; ++i)
#pragma unroll
            for (int j = 0; j < 4; ++j)
                acc[i][j] = __builtin_amdgcn_mfma_f32_16x16x32_bf16(
                    a[i], b[j], acc[i][j], 0, 0, 0);
        __syncthreads();
    }

    // epilogue: D[row=(lane>>4)*4+r][col=lane&15]; fused bias; bf16 store
#pragma unroll
    for (int j = 0; j < 4; ++j) {
        const int gc = n0 + wn + j * 16 + rr;
        const float bv = bias[e * DOUT + gc];
#pragma unroll
        for (int i = 0; i < 4; ++i) {
            const int gr = m0 + wm + i * 16 + (lane >> 4) * 4;
            unsigned short* cp = lgts + ((size_t)e * BSZ + gr) * DOUT + gc;
#pragma unroll
            for (int r = 0; r < 4; ++r)
                cp[(size_t)r * DOUT] = f32_to_bf16_rne(acc[i][j][r] + bv);
        }
    }
}

// ---------- 4. row stats: one wave per batch row; emit rinv4 + ev4 ---------
__global__ __launch_bounds__(256) void rowstats_kernel(
    const unsigned short* __restrict__ lg,
    float4* __restrict__ rinv4, float4* __restrict__ ev4) {
    const int b = blockIdx.x * 4 + (threadIdx.x >> 6);
    const int lane = threadIdx.x & 63;

    float pe[8];
    float Tv[3], Pv[2], rinv[4];
#pragma unroll
    for (int e = 0; e < NEXP; ++e) {
        short8 v = *(const short8*)&lg[((size_t)e * BSZ + b) * DOUT + lane * 8];
        float l[8];
#pragma unroll
        for (int j = 0; j < 8; ++j) l[j] = bf16_to_f32((unsigned short)v[j]);
        float ss = 0.f;
#pragma unroll
        for (int j = 0; j < 8; ++j) ss += l[j] * l[j];
        ss = wred(ss);
        float ri = 1.0f / fmaxf(sqrtf(ss), 1e-12f);
        rinv[e] = ri;
        float t = 0.f, p = 0.f;
        float ce[8];
#pragma unroll
        for (int j = 0; j < 8; ++j) {
            ce[j] = expf(l[j] * ri);
            t += ce[j];
            if (e > 0) p += pe[j] * ce[j];
        }
        if (e < 3) Tv[e] = wred(t);
        if (e >= 1 && e <= 2) Pv[e - 1] = wred(p);
#pragma unroll
        for (int j = 0; j < 8; ++j) pe[j] = ce[j];
    }

    if (lane == 0) {
        const float d = (float)DOUT;
        float S0 = Tv[0] + d, S1 = Tv[1] + d, S2 = Tv[2] + d;
        float u0 = d / S0, u1 = d / S1, u2 = d / S2;
        float sb0 = Tv[0] / S0, sb1 = Tv[1] / S1, sb2 = Tv[2] / S2;
        float C1 = sb0 * sb1 - Pv[0] / (S0 * S1);
        float C2 = sb1 * sb2 - Pv[1] / (S1 * S2);
        float w1 = u0;
        float w2 = w1 * u1 / (1.0f - C1);
        float w3 = w2 * u2 / (1.0f - C2);
        ev4[b] = make_float4(expf(5.0f), expf(5.0f * w1), expf(5.0f * w2),
                             expf(5.0f * w3));
        rinv4[b] = make_float4(rinv[0], rinv[1], rinv[2], rinv[3]);
    }
}

// ---------- 5. Z reduce per expert (single block) ----------
__global__ __launch_bounds__(1024) void zred_kernel(
    const float4* __restrict__ ev4, float4* __restrict__ invZ) {
    __shared__ float4 sred[16];
    float4 s = make_float4(0.f, 0.f, 0.f, 0.f);
    for (int b = threadIdx.x; b < BSZ; b += 1024) {
        float4 v = ev4[b];
        s.x += v.x; s.y += v.y; s.z += v.z; s.w += v.w;
    }
    for (int off = 1; off < 64; off <<= 1) {
        s.x += __shfl_xor(s.x, off, 64);
        s.y += __shfl_xor(s.y, off, 64);
        s.z += __shfl_xor(s.z, off, 64);
        s.w += __shfl_xor(s.w, off, 64);
    }
    const int lane = threadIdx.x & 63, w = threadIdx.x >> 6;
    if (lane == 0) sred[w] = s;
    __syncthreads();
    if (threadIdx.x == 0) {
        float4 t = make_float4(0.f, 0.f, 0.f, 0.f);
#pragma unroll
        for (int i = 0; i < 16; ++i) {
            t.x += sred[i].x; t.y += sred[i].y;
            t.z += sred[i].z; t.w += sred[i].w;
        }
        invZ[0] = make_float4(1.f / t.x, 1.f / t.y, 1.f / t.z, 1.f / t.w);
    }
}

// ---------- 6. weighted output: one wave per batch row ----------
__global__ __launch_bounds__(256) void outk_kernel(
    const unsigned short* __restrict__ lg,
    const float4* __restrict__ rinv4, const float4* __restrict__ ev4,
    const float4* __restrict__ invZ, float* __restrict__ out) {
    const int b = blockIdx.x * 4 + (threadIdx.x >> 6);
    const int lane = threadIdx.x & 63;
    float4 iz = invZ[0];
    float4 ri = rinv4[b];
    float4 ev = ev4[b];
    float wgt[4] = {ev.x * iz.x * ri.x, ev.y * iz.y * ri.y,
                    ev.z * iz.z * ri.z, ev.w * iz.w * ri.w};
    float o[8] = {0.f, 0.f, 0.f, 0.f, 0.f, 0.f, 0.f, 0.f};
#pragma unroll
    for (int e = 0; e < NEXP; ++e) {
        short8 v = *(const short8*)&lg[((size_t)e * BSZ + b) * DOUT + lane * 8];
#pragma unroll
        for (int j = 0; j < 8; ++j)
            o[j] += bf16_to_f32((unsigned short)v[j]) * wgt[e];
    }
    float* op = out + (size_t)b * DOUT + lane * 8;
    *(float4*)op = make_float4(o[0], o[1], o[2], o[3]);
    *(float4*)(op + 4) = make_float4(o[4], o[5], o[6], o[7]);
}

// ---------- launch ----------
extern "C" void kernel_launch(void* const* d_in, const int* in_sizes, int n_in,
                              void* d_out, int out_size, void* d_ws,
                              size_t ws_size, hipStream_t stream) {
    const float* x = (const float*)d_in[0];
    const float* W = (const float*)d_in[1];
    const float* bias = (const float*)d_in[2];
    float* out = (float*)d_out;

    char* ws = (char*)d_ws;
    // layout: lgts bf16 [4][8192][512] = 32MB | xb 16MB | wtb 4MB |
    //         rinv4 128KB | ev4 128KB | invZ 16B
    unsigned short* lgts = (unsigned short*)ws;
    unsigned short* xb  = (unsigned short*)(ws + (size_t)33554432);
    unsigned short* wtb = (unsigned short*)(ws + (size_t)50331648);
    float4* rinv4 = (float4*)(ws + (size_t)54525952);
    float4* ev4   = (float4*)(ws + (size_t)54525952 + 131072);
    float4* invZ  = (float4*)(ws + (size_t)54525952 + 262144);

    convx_kernel<<<4096, 256, 0, stream>>>(x, xb);
    convwt_kernel<<<dim3(DOUT / 32, DIN / 32, NEXP), 256, 0, stream>>>(W, wtb);
    gemm_kernel<<<1024, 256, 0, stream>>>(xb, wtb, bias, lgts);
    rowstats_kernel<<<BSZ / 4, 256, 0, stream>>>(lgts, rinv4, ev4);
    zred_kernel<<<1, 1024, 0, stream>>>(ev4, invZ);
    outk_kernel<<<BSZ / 4, 256, 0, stream>>>(lgts, rinv4, ev4, invZ, out);
}